// Round 4
// baseline (764.709 us; speedup 1.0000x reference)
//
#include <hip/hip_runtime.h>
#include <stdint.h>

// ---------------------------------------------------------------------------
// Uncond_MTPN_EncoderLayer: B=4 S=1024 D=1024 Fd=4096 M=512 H=16 HD=64 L=2
// Inputs fp32, output fp32, internal bf16 MFMA + fp32 accum.
// Round 14 == Round 13 resubmit (container infra failure, no kernel verdict).
// R13: flash_attn VALU-bound (40% VALU vs 13% Mfma at 2x48us):
//   - K/V register-prefetch (T14): tile t+1 global loads issued during tile t
//     compute; LDS write next iter (latency hidden under MFMA+softmax)
//   - v_cvt_pk_bf16_f32 packed P conversion (1 op/2 vals vs ~4 ops/val RNE)
//   - Q fragments hoisted out of the KV loop (loop-invariant); Qs buffer
//     reused as Ps -> LDS 38.9->29.2 KB, -2 ds_read_b128/tile/wave
// gemm128n (R12) kept: counted-vmcnt ring, 2 blocks/CU.
// ---------------------------------------------------------------------------

typedef short   s16x8 __attribute__((ext_vector_type(8)));
typedef float   f32x4 __attribute__((ext_vector_type(4)));
typedef uint16_t u16x8 __attribute__((ext_vector_type(8)));
typedef uint16_t u16x4 __attribute__((ext_vector_type(4)));

__device__ __forceinline__ float bf2f(uint16_t h) {
    union { uint32_t u; float f; } c; c.u = ((uint32_t)h) << 16; return c.f;
}
__device__ __forceinline__ uint16_t f2bf(float f) {
    union { float f; uint32_t u; } c; c.f = f;
    uint32_t u = c.u;
    u += 0x7fffu + ((u >> 16) & 1u);       // round-to-nearest-even
    return (uint16_t)(u >> 16);
}
// packed RNE f32x2 -> bf16x2 (hardware; same rounding as f2bf)
__device__ __forceinline__ uint32_t cvt_pk_bf16(float lo, float hi) {
    uint32_t r;
    asm("v_cvt_pk_bf16_f32 %0, %1, %2" : "=v"(r) : "v"(lo), "v"(hi));
    return r;
}

__device__ __forceinline__ void g2l16(const uint16_t* g, uint16_t* l) {
    __builtin_amdgcn_global_load_lds(
        (const __attribute__((address_space(1))) void*)g,
        (__attribute__((address_space(3))) void*)l, 16, 0, 0);
}

// ---------------------------------------------------------------------------
// gemm128n: C[4096,N] = A[4096,1024] @ Bt[N,1024]^T + bias.  K=1024 fixed.
// 128x256 tile, 256 threads (4 waves, 1M x 4N), BK=32, 3-slot LDS ring (72KB)
// -> 2 blocks/CU.  Per K-tile: {stage(t+2); 12 ds_read_b128; lgkmcnt(0);
// 32 MFMA; vmcnt(6); s_barrier}.  Counted vmcnt keeps 6 loads in flight
// across the barrier; co-resident block fills residual stalls.
// MODE 1: bias+relu -> C0.  MODE 3: QKV fused (Q->C0, K->C1, V^T->C2).
// Hazards: stage(t+2)->slot (t-1)%3, readers drained at tile-(t-1) barrier;
// vmcnt(6)+barrier at tile end lands tile t+1 for ALL waves.
// Grid: 32 m-blocks = 8 XCD groups x 4; id&7 selects XCD group, n streamed.
// ---------------------------------------------------------------------------
template<int MODE>
__global__ __launch_bounds__(256, 2) void gemm128n(
    const uint16_t* __restrict__ A, const uint16_t* __restrict__ Bt,
    const float* __restrict__ bias0, const float* __restrict__ bias1,
    const float* __restrict__ bias2,
    uint16_t* __restrict__ C0, uint16_t* __restrict__ C1,
    uint16_t* __restrict__ C2,
    int N)
{
    // ring: A 3 x (128x32) = 24 KB, B 3 x (256x32) = 48 KB; epilogue 66 KB
    __shared__ __align__(16) uint16_t smem[36864];
    uint16_t* sA = smem;             // 3 x 4096 elems
    uint16_t* sB = smem + 12288;     // 3 x 8192 elems

    const int t    = threadIdx.x;
    const int w    = t >> 6;
    const int lane = t & 63;
    const int qd   = lane >> 4;
    const int cc   = lane & 15;
    const int wn   = w * 64;

    const int id  = blockIdx.x;
    const int loc = id >> 3;
    const int bm  = (id & 7) * 4 + (loc & 3);   // 32 m-blocks: 8 XCDs x 4
    const int bn  = loc >> 2;
    const int m0  = bm * 128;
    const int n0  = bn * 256;

    const float* bp = bias0;
    int n0c = n0;
    if (MODE == 3) {
        int seg = n0 >> 10;
        n0c = n0 & 1023;
        bp = (seg == 0) ? bias0 : (seg == 1) ? bias1 : bias2;
    }
    float bb[4];
#pragma unroll
    for (int j = 0; j < 4; ++j) bb[j] = bp[n0c + wn + j * 16 + cc];

    // fragment read offsets (XOR swizzle on 16B k-chunks; key = (row>>1)&3)
    int offA[8], offB[4];
#pragma unroll
    for (int i = 0; i < 8; ++i) {
        int ml = i * 16 + cc;
        offA[i] = ml * 32 + ((qd ^ ((ml >> 1) & 3)) * 8);
    }
#pragma unroll
    for (int j = 0; j < 4; ++j) {
        int nl = wn + j * 16 + cc;
        offB[j] = nl * 32 + ((qd ^ ((nl >> 1) & 3)) * 8);
    }

    // staging maps (pre-swizzled global source, linear LDS dest)
    const uint16_t* pA[2]; int ldA[2];
#pragma unroll
    for (int is = 0; is < 2; ++is) {
        int gc = is * 256 + t;
        int row = gc >> 2, ph = gc & 3;
        pA[is]  = A + (size_t)(m0 + row) * 1024 + (ph ^ ((row >> 1) & 3)) * 8;
        ldA[is] = (is * 256 + w * 64) * 8;
    }
    const uint16_t* pB[4]; int ldB[4];
#pragma unroll
    for (int is = 0; is < 4; ++is) {
        int gc = is * 256 + t;
        int row = gc >> 2, ph = gc & 3;
        pB[is]  = Bt + (size_t)(n0 + row) * 1024 + (ph ^ ((row >> 1) & 3)) * 8;
        ldB[is] = (is * 256 + w * 64) * 8;
    }
    auto stage = [&](int tt, int slot) {
        int kt = tt * 32;
        uint16_t* dA = sA + slot * 4096;
        uint16_t* dB = sB + slot * 8192;
#pragma unroll
        for (int is = 0; is < 2; ++is) g2l16(pA[is] + kt, dA + ldA[is]);
#pragma unroll
        for (int is = 0; is < 4; ++is) g2l16(pB[is] + kt, dB + ldB[is]);
    };

    f32x4 acc[8][4];
#pragma unroll
    for (int i = 0; i < 8; ++i)
#pragma unroll
        for (int j = 0; j < 4; ++j) acc[i][j] = (f32x4)0.0f;

    // prologue: tiles 0,1 in flight; land tile 0 (12 issued, keep 6)
    stage(0, 0); stage(1, 1);
    asm volatile("s_waitcnt vmcnt(6)" ::: "memory");
    __builtin_amdgcn_s_barrier();

    int cur = 0, pf = 2;
#pragma unroll 1
    for (int kt = 0; kt < 32; ++kt) {
        const uint16_t* sa = sA + cur * 4096;
        const uint16_t* sb = sB + cur * 8192;
        s16x8 av[8], bv[4];
#pragma unroll
        for (int j = 0; j < 4; ++j) bv[j] = *(const s16x8*)(sb + offB[j]);
#pragma unroll
        for (int i = 0; i < 8; ++i) av[i] = *(const s16x8*)(sa + offA[i]);
        if (kt < 30) stage(kt + 2, pf);        // issue while ds_reads in flight
        asm volatile("s_waitcnt lgkmcnt(0)" ::: "memory");
        __builtin_amdgcn_sched_barrier(0);
        __builtin_amdgcn_s_setprio(1);
#pragma unroll
        for (int i = 0; i < 8; ++i)
#pragma unroll
            for (int j = 0; j < 4; ++j)
                acc[i][j] = __builtin_amdgcn_mfma_f32_16x16x32_bf16(
                    av[i], bv[j], acc[i][j], 0, 0, 0);
        __builtin_amdgcn_s_setprio(0);
        // tile kt+1 (oldest 6 of <=12 outstanding) must land before barrier
        if (kt < 30)       { asm volatile("s_waitcnt vmcnt(6)" ::: "memory"); }
        else if (kt == 30) { asm volatile("s_waitcnt vmcnt(0)" ::: "memory"); }
        __builtin_amdgcn_s_barrier();
        pf = cur;
        cur = (cur == 2) ? 0 : cur + 1;
    }

    // ------------------------------ epilogue -------------------------------
    // C/D layout: col=lane&15, row=(lane>>4)*4+reg  [m89 verified]
    if (MODE == 3 && (n0 >> 10) == 2) {
        // V^T: C2[((b*16+hh)*64+d)*1024 + s], 4 consecutive s per u16x4
#pragma unroll
        for (int j = 0; j < 4; ++j) {
            int c = n0c + wn + j * 16 + cc;
            int hh = c >> 6, d = c & 63;
#pragma unroll
            for (int i = 0; i < 8; ++i) {
                int rb = m0 + i * 16 + qd * 4;
                int b = rb >> 10, s = rb & 1023;
                u16x4 o;
#pragma unroll
                for (int r = 0; r < 4; ++r) o[r] = f2bf(acc[i][j][r] + bb[j]);
                *(u16x4*)(C2 + ((size_t)((b * 16 + hh) * 64 + d)) * 1024 + s) = o;
            }
        }
        return;
    }
    {
        uint16_t* C = C0;
        int Nc = N;
        if (MODE == 3) {
            int seg = n0 >> 10;
            C = (seg == 0) ? C0 : C1;
            Nc = 1024;
        }
        constexpr int ST = 264;            // 256 + 8 pad
        // final K-loop barrier followed all lgkmcnt(0) drains: smem is dead
#pragma unroll
        for (int i = 0; i < 8; ++i)
#pragma unroll
            for (int j = 0; j < 4; ++j) {
                f32x4 v = acc[i][j];
#pragma unroll
                for (int r = 0; r < 4; ++r) {
                    float val = v[r] + bb[j];
                    if (MODE == 1) val = fmaxf(val, 0.0f);
                    smem[(i * 16 + qd * 4 + r) * ST + wn + j * 16 + cc] = f2bf(val);
                }
            }
        __syncthreads();
#pragma unroll
        for (int p = 0; p < 16; ++p) {
            int row  = p * 8 + (t >> 5);
            int colc = (t & 31) * 8;
            u16x8 v = *(const u16x8*)(smem + row * ST + colc);
            *(u16x8*)(C + (size_t)(m0 + row) * Nc + n0c + colc) = v;
        }
    }
}

// ---------------------------------------------------------------------------
// GEMM: C[M,N] = A[M,K] @ B[K,N] + bias, B supplied as Bt[N,K] (bf16).
// MODE 0: bias -> C0 (LDS-exchange vectorized epilogue).
// MODE 1: bias+relu -> C0 (same epilogue).
// MODE 3: QKV fused: col<1024 -> Q=C0, col<2048 -> K=C1, else V^T -> C2
//         (scalar epilogue; V^T is a scatter anyway).
// BN in {64,128}, BK in {32,64}, DB in {0,1} (double-buffered prefetch).
// LDS XOR swizzle on 16B k-chunks keeps ds_read_b128 at 2-way (free, m136).
// Grid remap: id%8 (~XCD) selects an m-panel group; n streamed within group.
// ---------------------------------------------------------------------------
template<int MODE, int BN, int BK, int DB>
__global__ __launch_bounds__(256) void gemm_bt(
    const uint16_t* __restrict__ A, const uint16_t* __restrict__ Bt,
    const float* __restrict__ bias0, const float* __restrict__ bias1,
    const float* __restrict__ bias2,
    uint16_t* __restrict__ C0, uint16_t* __restrict__ C1,
    uint16_t* __restrict__ C2,
    int M, int N, int K)
{
    constexpr int JN   = BN / 32;
    constexpr int KS   = BK / 32;
    constexpr int CPR  = BK / 8;
    constexpr int LG   = (BK == 32) ? 2 : 3;
    constexpr int RA   = (128 * BK / 8) / 256;
    constexpr int RB   = (BN  * BK / 8) / 256;
    constexpr int NBUF = DB ? 2 : 1;
    constexpr int STG  = NBUF * (128 + BN) * BK;           // staging elems
    constexpr int EPI  = (MODE == 3) ? 0 : 128 * (BN + 8); // exchange elems
    constexpr int SMEM = (STG > EPI) ? STG : EPI;
    __shared__ __align__(16) uint16_t smem[SMEM];
    uint16_t* sAp = smem;                          // [NBUF][128*BK]
    uint16_t* sBp = smem + NBUF * 128 * BK;        // [NBUF][BN*BK]

    const int t    = threadIdx.x;
    const int w    = t >> 6;
    const int lane = t & 63;
    const int qd   = lane >> 4;
    const int cc   = lane & 15;

    int bm, bn;
    {
        int gx = gridDim.x, gy = gridDim.y;
        if ((gy & 7) == 0) {
            int id   = blockIdx.y * gx + blockIdx.x;
            int gpg  = gy >> 3;
            int rest = id >> 3;
            bm = (id & 7) * gpg + rest % gpg;
            bn = rest / gpg;
        } else { bm = blockIdx.y; bn = blockIdx.x; }
    }
    const int m0 = bm * 128;
    const int n0 = bn * BN;
    const int wm = (w >> 1) * 64;
    const int wn = (w & 1) * (BN / 2);

    auto key = [](int row) -> int {
        return (BK == 32) ? ((row >> 1) & 3) : (row & 7);
    };

    f32x4 acc[4][JN];
#pragma unroll
    for (int i = 0; i < 4; ++i)
#pragma unroll
        for (int j = 0; j < JN; ++j) acc[i][j] = (f32x4)0.0f;

    int rA[RA], kA[RA];
#pragma unroll
    for (int is = 0; is < RA; ++is) {
        int gc = is * 256 + t;
        int row = gc >> LG, ph = gc & (CPR - 1);
        rA[is] = row;
        kA[is] = (ph ^ key(row)) * 8;
    }
    int rB[RB], kB[RB];
#pragma unroll
    for (int is = 0; is < RB; ++is) {
        int gc = is * 256 + t;
        int row = gc >> LG, ph = gc & (CPR - 1);
        rB[is] = row;
        kB[is] = (ph ^ key(row)) * 8;
    }
    int offA[4][KS], offB[JN][KS];
#pragma unroll
    for (int i = 0; i < 4; ++i) {
        int ml = wm + i * 16 + cc;
#pragma unroll
        for (int ks = 0; ks < KS; ++ks)
            offA[i][ks] = ml * BK + ((ks * 4 + qd) ^ key(ml)) * 8;
    }
#pragma unroll
    for (int j = 0; j < JN; ++j) {
        int nl = wn + j * 16 + cc;
#pragma unroll
        for (int ks = 0; ks < KS; ++ks)
            offB[j][ks] = nl * BK + ((ks * 4 + qd) ^ key(nl)) * 8;
    }

    auto stage = [&](int kt, int buf) {
#pragma unroll
        for (int is = 0; is < RA; ++is)
            g2l16(A + (size_t)(m0 + rA[is]) * K + kt + kA[is],
                  sAp + (size_t)buf * 128 * BK + (size_t)(is * 256 + w * 64) * 8);
#pragma unroll
        for (int is = 0; is < RB; ++is)
            g2l16(Bt + (size_t)(n0 + rB[is]) * K + kt + kB[is],
                  sBp + (size_t)buf * BN * BK + (size_t)(is * 256 + w * 64) * 8);
    };
    auto compute = [&](int buf) {
        const uint16_t* sa = sAp + (size_t)buf * 128 * BK;
        const uint16_t* sb = sBp + (size_t)buf * BN * BK;
#pragma unroll
        for (int ks = 0; ks < KS; ++ks) {
            s16x8 af[4], bv[JN];
#pragma unroll
            for (int i = 0; i < 4; ++i) af[i] = *(const s16x8*)(sa + offA[i][ks]);
#pragma unroll
            for (int j = 0; j < JN; ++j) bv[j] = *(const s16x8*)(sb + offB[j][ks]);
#pragma unroll
            for (int i = 0; i < 4; ++i)
#pragma unroll
                for (int j = 0; j < JN; ++j)
                    acc[i][j] = __builtin_amdgcn_mfma_f32_16x16x32_bf16(
                        af[i], bv[j], acc[i][j], 0, 0, 0);
        }
    };

    if (DB) {
        stage(0, 0);
        __syncthreads();
        int cur = 0;
        for (int kt = 0; kt < K; kt += BK) {
            if (kt + BK < K) stage(kt + BK, cur ^ 1);
            compute(cur);
            __syncthreads();
            cur ^= 1;
        }
    } else {
        for (int kt = 0; kt < K; kt += BK) {
            stage(kt, 0);
            __syncthreads();
            compute(0);
            __syncthreads();
        }
    }

    // C/D layout: col=lane&15, row=(lane>>4)*4+reg  [m89 verified]
    if (MODE == 3) {
#pragma unroll
        for (int j = 0; j < JN; ++j) {
            int col = n0 + wn + j * 16 + cc;
            int seg = col >> 10;
            const float* bp = (seg == 0) ? bias0 : (seg == 1) ? bias1 : bias2;
            float bb = bp[col & 1023];
#pragma unroll
            for (int i = 0; i < 4; ++i) {
                f32x4 v = acc[i][j];
#pragma unroll
                for (int r = 0; r < 4; ++r) {
                    float val = v[r] + bb;
                    int row = m0 + wm + i * 16 + qd * 4 + r;
                    if (col < 1024) {
                        C0[(size_t)row * 1024 + col] = f2bf(val);
                    } else if (col < 2048) {
                        C1[(size_t)row * 1024 + (col - 1024)] = f2bf(val);
                    } else {
                        int c = col - 2048;
                        int b = row >> 10, s = row & 1023;
                        int hh = c >> 6, d = c & 63;
                        C2[((size_t)(b * 16 + hh) * 64 + d) * 1024 + s] = f2bf(val);
                    }
                }
            }
        }
    } else {
        // LDS-exchange epilogue: scatter to padded tile, vector readback/store
        constexpr int ST = BN + 8;           // elem stride: 2-way max aliasing
        // (final __syncthreads of the K-loop already protects smem reuse)
#pragma unroll
        for (int j = 0; j < JN; ++j) {
            int col = wn + j * 16 + cc;
            float bb = bias0[n0 + col];
#pragma unroll
            for (int i = 0; i < 4; ++i) {
                f32x4 v = acc[i][j];
#pragma unroll
                for (int r = 0; r < 4; ++r) {
                    float val = v[r] + bb;
                    if (MODE == 1) val = fmaxf(val, 0.0f);
                    smem[(wm + i * 16 + qd * 4 + r) * ST + col] = f2bf(val);
                }
            }
        }
        __syncthreads();
        constexpr int NP  = 128 * BN / 2048;   // u16x8 rounds (8 or 4)
        constexpr int TPR = BN / 8;            // threads per row (16 or 8)
#pragma unroll
        for (int p = 0; p < NP; ++p) {
            int row  = p * (256 / TPR) + t / TPR;
            int colc = (t % TPR) * 8;
            u16x8 v = *(const u16x8*)(smem + row * ST + colc);
            *(u16x8*)(C0 + (size_t)(m0 + row) * N + n0 + colc) = v;
        }
    }
}

// ---------------------------------------------------------------------------
// Flash attention, no-max softmax (scores tiny; softmax shift-invariant).
// Block = (64 q rows, head).  1D grid 1024; id&7 (~XCD) owns heads 8x..8x+7.
// Pad 76 elem (152 B): frag reads/Ps writes land 2 lanes/bank (free).
// R13: K/V reg-prefetch (T14), packed cvt_pk P-stores, Q frags hoisted
// (QPs buffer = Q staging, then reused as P exchange; 29.2 KB LDS).
// ---------------------------------------------------------------------------
#define FA_P 76
__global__ __launch_bounds__(256) void flash_attn(
    const uint16_t* __restrict__ Q, const uint16_t* __restrict__ K,
    const uint16_t* __restrict__ Vt, uint16_t* __restrict__ O)
{
    __shared__ __align__(16) uint16_t QPs[64 * FA_P];  // Q stage, then P
    __shared__ __align__(16) uint16_t Ks[64 * FA_P];
    __shared__ __align__(16) uint16_t Vs[64 * FA_P];   // Vs[d][kpos]

    const int t    = threadIdx.x;
    const int w    = t >> 6;
    const int lane = t & 63;
    const int qd   = lane >> 4;
    const int cc   = lane & 15;
    const int id   = blockIdx.x;
    const int xg   = id & 7;
    const int loc  = id >> 3;
    const int bh   = xg * 8 + (loc >> 4);
    const int qblk = loc & 15;
    const int b    = bh >> 4, hh = bh & 15;
    const size_t rowbase = (size_t)b * 1024;

    // staging geometry: thread covers 2 chunks (row, 8-elem chunk)
    int rr[2], ch8[2], lws[2];
    const uint16_t* Kp[2];
    const uint16_t* Vp[2];
#pragma unroll
    for (int is = 0; is < 2; ++is) {
        int c   = is * 256 + t;
        rr[is]  = c >> 3;
        ch8[is] = (c & 7) * 8;
        lws[is] = rr[is] * FA_P + ch8[is];
        Kp[is]  = K  + (rowbase + rr[is]) * 1024 + hh * 64 + ch8[is];
        Vp[is]  = Vt + ((size_t)(bh * 64 + rr[is])) * 1024 + ch8[is];
    }

    // prefetch K/V tile 0 into regs (lands during Q staging + barriers)
    u16x8 kr[2], vr[2];
#pragma unroll
    for (int is = 0; is < 2; ++is) {
        kr[is] = *(const u16x8*)(Kp[is]);
        vr[is] = *(const u16x8*)(Vp[is]);
    }

    // stage Q, hoist fragments to regs (loop-invariant)
#pragma unroll
    for (int is = 0; is < 2; ++is)
        *(u16x8*)(QPs + lws[is]) =
            *(const u16x8*)(Q + (rowbase + qblk * 64 + rr[is]) * 1024 + hh * 64 + ch8[is]);
    __syncthreads();
    s16x8 aq0 = *(const s16x8*)(QPs + (w * 16 + cc) * FA_P + qd * 8);
    s16x8 aq1 = *(const s16x8*)(QPs + (w * 16 + cc) * FA_P + 32 + qd * 8);
    __syncthreads();   // drains lgkm: all waves' Q reads done before P writes

    f32x4 o[4];
    float lrow[4] = {0.0f, 0.0f, 0.0f, 0.0f};
#pragma unroll
    for (int j = 0; j < 4; ++j) o[j] = (f32x4)0.0f;

#pragma unroll 1
    for (int kb = 64; kb <= 1024; kb += 64) {
        // write prefetched tile to LDS (regs free after issue)
#pragma unroll
        for (int is = 0; is < 2; ++is) {
            *(u16x8*)(Ks + lws[is]) = kr[is];
            *(u16x8*)(Vs + lws[is]) = vr[is];
        }
        if (kb < 1024) {   // issue next tile's loads; land during compute
#pragma unroll
            for (int is = 0; is < 2; ++is) {
                kr[is] = *(const u16x8*)(Kp[is] + (size_t)kb * 1024);
                vr[is] = *(const u16x8*)(Vp[is] + kb);
            }
        }
        __syncthreads();

        f32x4 sc[4];
#pragma unroll
        for (int j = 0; j < 4; ++j) {
            s16x8 b0 = *(const s16x8*)(Ks + (j * 16 + cc) * FA_P + qd * 8);
            s16x8 b1 = *(const s16x8*)(Ks + (j * 16 + cc) * FA_P + 32 + qd * 8);
            sc[j] = __builtin_amdgcn_mfma_f32_16x16x32_bf16(aq0, b0, (f32x4)0.0f, 0, 0, 0);
            sc[j] = __builtin_amdgcn_mfma_f32_16x16x32_bf16(aq1, b1, sc[j], 0, 0, 0);
        }

#pragma unroll
        for (int r = 0; r < 4; ++r) {
            float p0 = __expf(sc[0][r] * 0.125f);
            float p1 = __expf(sc[1][r] * 0.125f);
            float p2 = __expf(sc[2][r] * 0.125f);
            float p3 = __expf(sc[3][r] * 0.125f);
            lrow[r] += (p0 + p1) + (p2 + p3);
            int prow = (w * 16 + qd * 4 + r) * FA_P + cc;
            uint32_t pk01 = cvt_pk_bf16(p0, p1);
            uint32_t pk23 = cvt_pk_bf16(p2, p3);
            QPs[prow]      = (uint16_t)pk01;
            QPs[prow + 16] = (uint16_t)(pk01 >> 16);
            QPs[prow + 32] = (uint16_t)pk23;
            QPs[prow + 48] = (uint16_t)(pk23 >> 16);
        }

        // P rows w*16..w*16+15 written and read by the SAME wave: no barrier
#pragma unroll
        for (int ks = 0; ks < 2; ++ks) {
            s16x8 ap = *(const s16x8*)(QPs + (w * 16 + cc) * FA_P + ks * 32 + qd * 8);
#pragma unroll
            for (int j = 0; j < 4; ++j) {
                s16x8 bv = *(const s16x8*)(Vs + (j * 16 + cc) * FA_P + ks * 32 + qd * 8);
                o[j] = __builtin_amdgcn_mfma_f32_16x16x32_bf16(ap, bv, o[j], 0, 0, 0);
            }
        }
        __syncthreads();   // all Ks/Vs reads done -> next iter may overwrite
    }

#pragma unroll
    for (int r = 0; r < 4; ++r) {
        float rs = lrow[r];
        rs += __shfl_xor(rs, 1);
        rs += __shfl_xor(rs, 2);
        rs += __shfl_xor(rs, 4);
        rs += __shfl_xor(rs, 8);
        float inv = 1.0f / rs;
        size_t grow = rowbase + qblk * 64 + w * 16 + qd * 4 + r;
#pragma unroll
        for (int j = 0; j < 4; ++j)
            O[grow * 1024 + hh * 64 + j * 16 + cc] = f2bf(o[j][r] * inv);
    }
}

// ---------------------------------------------------------------------------
// out = LayerNorm(A + B) * scale + bias over rows of 1024.
// A bf16;  B bf16 (BT=0) or fp32 (BT=1);  scale/bias fp32.
// F32OUT=1 stores fp32 (the network output); else bf16.  1 block/row.
// ---------------------------------------------------------------------------
template<int BT, int F32OUT>
__global__ __launch_bounds__(256) void ln_res(
    const uint16_t* __restrict__ A, const void* __restrict__ Bp,
    const float* __restrict__ S, const float* __restrict__ Bi,
    void* __restrict__ outp)
{
    const int row = blockIdx.x, t = threadIdx.x;
    const int w = t >> 6, lane = t & 63;
    u16x4 a4 = *(const u16x4*)(A + (size_t)row * 1024 + t * 4);
    float bvals[4];
    if (BT == 0) {
        u16x4 b4 = *(const u16x4*)((const uint16_t*)Bp + (size_t)row * 1024 + t * 4);
#pragma unroll
        for (int e = 0; e < 4; ++e) bvals[e] = bf2f(b4[e]);
    } else {
        float4 b4 = *(const float4*)((const float*)Bp + (size_t)row * 1024 + t * 4);
        bvals[0] = b4.x; bvals[1] = b4.y; bvals[2] = b4.z; bvals[3] = b4.w;
    }
    float v[4], sum = 0.0f, sq = 0.0f;
#pragma unroll
    for (int e = 0; e < 4; ++e) {
        v[e] = bf2f(a4[e]) + bvals[e];
        sum += v[e];
        sq  += v[e] * v[e];
    }
#pragma unroll
    for (int d = 1; d < 64; d <<= 1) {
        sum += __shfl_xor(sum, d);
        sq  += __shfl_xor(sq, d);
    }
    __shared__ float rs[4], rq[4];
    if (lane == 0) { rs[w] = sum; rq[w] = sq; }
    __syncthreads();
    sum = rs[0] + rs[1] + rs[2] + rs[3];
    sq  = rq[0] + rq[1] + rq[2] + rq[3];
    float mean = sum * (1.0f / 1024.0f);
    float var  = sq * (1.0f / 1024.0f) - mean * mean;
    float rstd = rsqrtf(var + 1e-5f);
    float4 s4  = *(const float4*)(S + t * 4);
    float4 bi4 = *(const float4*)(Bi + t * 4);
    float r0 = (v[0] - mean) * rstd * s4.x + bi4.x;
    float r1 = (v[1] - mean) * rstd * s4.y + bi4.y;
    float r2 = (v[2] - mean) * rstd * s4.z + bi4.z;
    float r3 = (v[3] - mean) * rstd * s4.w + bi4.w;
    if (F32OUT) {
        *(float4*)((float*)outp + (size_t)row * 1024 + t * 4) =
            make_float4(r0, r1, r2, r3);
    } else {
        u16x4 o4;
        o4[0] = f2bf(r0); o4[1] = f2bf(r1); o4[2] = f2bf(r2); o4[3] = f2bf(r3);
        *(u16x4*)((uint16_t*)outp + (size_t)row * 1024 + t * 4) = o4;
    }
}

// out = g + pad(y2) + pad(y4); in-place on g is safe (pure per-element)
__global__ __launch_bounds__(256) void add3(
    const uint16_t* __restrict__ g, const uint16_t* __restrict__ y2,
    const uint16_t* __restrict__ y4, uint16_t* __restrict__ out)
{
    size_t e = ((size_t)blockIdx.x * 256 + threadIdx.x) * 4;
    int row = (int)(e >> 10), col = (int)(e & 1023);
    int b = row >> 10, s = row & 1023;
    u16x4 gv = *(const u16x4*)(g + e);
    float v[4];
#pragma unroll
    for (int k = 0; k < 4; ++k) v[k] = bf2f(gv[k]);
    if (s >= 512) {
        u16x4 a = *(const u16x4*)(y2 + ((size_t)(b * 512 + s - 512)) * 1024 + col);
#pragma unroll
        for (int k = 0; k < 4; ++k) v[k] += bf2f(a[k]);
    }
    if (s >= 768) {
        u16x4 a = *(const u16x4*)(y4 + ((size_t)(b * 256 + s - 768)) * 1024 + col);
#pragma unroll
        for (int k = 0; k < 4; ++k) v[k] += bf2f(a[k]);
    }
    u16x4 o4;
#pragma unroll
    for (int k = 0; k < 4; ++k) o4[k] = f2bf(v[k]);
    *(u16x4*)(out + e) = o4;
}

// gather last-st rows per batch from fp32 x, emit bf16
__global__ __launch_bounds__(256) void copy_rows_f32(
    const float* __restrict__ x, uint16_t* __restrict__ out, int lgst)
{
    size_t e = ((size_t)blockIdx.x * 256 + threadIdx.x) * 4;
    int row = (int)(e >> 10), col = (int)(e & 1023);
    int st = 1 << lgst;
    int b = row >> lgst, s = row & (st - 1);
    float4 a = *(const float4*)(x + ((size_t)(b * 1024 + (1024 - st) + s)) * 1024 + col);
    u16x4 o4;
    o4[0] = f2bf(a.x); o4[1] = f2bf(a.y); o4[2] = f2bf(a.z); o4[3] = f2bf(a.w);
    *(u16x4*)(out + e) = o4;
}

// Wt[N,K] = bf16(W[K,N]^T), fp32 source.  64x64 tiles, float4 in, u16x8 out.
__global__ __launch_bounds__(256) void transpose_k(
    const float* __restrict__ W, uint16_t* __restrict__ Wt, int Kd, int Nd)
{
    __shared__ uint16_t tile[64][68];
    const int t  = threadIdx.x;
    const int n0 = blockIdx.x * 64, k0 = blockIdx.y * 64;
#pragma unroll
    for (int p = 0; p < 4; ++p) {
        int k  = p * 16 + (t >> 4);
        int nn = (t & 15) * 4;
        float4 a = *(const float4*)(W + (size_t)(k0 + k) * Nd + n0 + nn);
        tile[nn + 0][k] = f2bf(a.x);
        tile[nn + 1][k] = f2bf(a.y);
        tile[nn + 2][k] = f2bf(a.z);
        tile[nn + 3][k] = f2bf(a.w);
    }
    __syncthreads();
#pragma unroll
    for (int p = 0; p < 2; ++p) {
        int nn = p * 32 + (t >> 3);
        int kk = (t & 7) * 8;
        u16x8 o = *(const u16x8*)(&tile[nn][kk]);
        *(u16x8*)(Wt + (size_t)(n0 + nn) * Kd + k0 + kk) = o;
    }
}

// fp32 -> bf16 bulk convert
__global__ __launch_bounds__(256) void cvt(
    const float* __restrict__ src, uint16_t* __restrict__ dst)
{
    size_t i = ((size_t)blockIdx.x * 256 + threadIdx.x) * 8;
    float4 a = *(const float4*)(src + i);
    float4 b = *(const float4*)(src + i + 4);
    u16x8 o;
    o[0] = f2bf(a.x); o[1] = f2bf(a.y); o[2] = f2bf(a.z); o[3] = f2bf(a.w);
    o[4] = f2bf(b.x); o[5] = f2bf(b.y); o[6] = f2bf(b.z); o[7] = f2bf(b.w);
    *(u16x8*)(dst + i) = o;
}

// ---------------------------------------------------------------------------
extern "C" void kernel_launch(void* const* d_in, const int* in_sizes, int n_in,
                              void* d_out, int out_size, void* d_ws, size_t ws_size,
                              hipStream_t stream)
{
    const float* x    = (const float*)d_in[0];
    const float* Wq   = (const float*)d_in[1];
    const float* bq   = (const float*)d_in[2];
    const float* Wk   = (const float*)d_in[3];
    const float* bk   = (const float*)d_in[4];
    const float* Wv   = (const float*)d_in[5];
    const float* bv   = (const float*)d_in[6];
    const float* Wo   = (const float*)d_in[7];
    const float* bo   = (const float*)d_in[8];
    const float* W1   = (const float*)d_in[9];
    const float* b1   = (const float*)d_in[10];
    const float* W2   = (const float*)d_in[11];
    const float* b2   = (const float*)d_in[12];
    const float* n1s  = (const float*)d_in[13];
    const float* n1b  = (const float*)d_in[14];
    const float* n2s  = (const float*)d_in[15];
    const float* n2b  = (const float*)d_in[16];
    const float* ln1s = (const float*)d_in[17];
    const float* ln1b = (const float*)d_in[18];
    const float* ln2s = (const float*)d_in[19];
    const float* ln2b = (const float*)d_in[20];
    const float* ln3s = (const float*)d_in[21];
    const float* ln3b = (const float*)d_in[22];
    const float* Wb   = (const float*)d_in[23];
    const float* bb   = (const float*)d_in[24];
    const float* Wm   = (const float*)d_in[25];
    const float* bm   = (const float*)d_in[26];
    const float* Wf1  = (const float*)d_in[27];
    const float* bf1  = (const float*)d_in[28];
    const float* Wf2  = (const float*)d_in[29];
    const float* bf2  = (const float*)d_in[30];

    // ---- 64 MiB workspace layout ------------------------------------------
    char* ws = (char*)d_ws;
    const size_t MB = (size_t)1 << 20;
    uint16_t* g    = (uint16_t*)(ws);
    uint16_t* tb   = (uint16_t*)(ws + 8 * MB);
    char*     big  = ws + 16 * MB;
    uint16_t* qb   = (uint16_t*)(big);
    uint16_t* kbuf = (uint16_t*)(big + 8 * MB);
    uint16_t* vtb  = (uint16_t*)(big + 16 * MB);
    uint16_t* ob   = (uint16_t*)(big + 24 * MB);
    uint16_t* ffb  = (uint16_t*)(big);            // 32 MiB, attn bufs dead
    uint16_t* xbf  = (uint16_t*)(ws + 48 * MB);
    uint16_t* hb   = (uint16_t*)(ws + 48 * MB);   // reuses xbf slot
    uint16_t* wT   = (uint16_t*)(ws + 56 * MB);

    auto T = [&](const float* Wsrc, int Kd, int Nd, uint16_t* dst) {
        transpose_k<<<dim3(Nd / 64, Kd / 64), 256, 0, stream>>>(Wsrc, dst, Kd, Nd);
    };

    cvt<<<2048, 256, 0, stream>>>(x, xbf);   // 4M elements

    const uint16_t* gin = xbf;
    for (int i = 0; i < 2; ++i) {
        const size_t wOff = (size_t)i * 1024 * 1024;
        const size_t fOff = (size_t)i * 1024 * 4096;
        // fused QKV: wT = [Wq^T ; Wk^T ; Wv^T]  (3072 x 1024 bf16 = 6 MiB)
        T(Wq + wOff, 1024, 1024, wT);
        T(Wk + wOff, 1024, 1024, wT + (size_t)1024 * 1024);
        T(Wv + wOff, 1024, 1024, wT + (size_t)2048 * 1024);
        gemm128n<3><<<384, 256, 0, stream>>>(
            gin, wT, bq + i * 1024, bk + i * 1024, bv + i * 1024,
            qb, kbuf, vtb, 3072);
        flash_attn<<<1024, 256, 0, stream>>>(qb, kbuf, vtb, ob);
        T(Wo + wOff, 1024, 1024, wT);
        gemm_bt<0, 64, 64, 1><<<dim3(16, 32), 256, 0, stream>>>(
            ob, wT, bo + i * 1024, nullptr, nullptr, tb, nullptr, nullptr,
            4096, 1024, 1024);
        ln_res<0, 0><<<4096, 256, 0, stream>>>(gin, tb, n1s + i * 1024, n1b + i * 1024, g);
        // FF: ffb overlays qb/kbuf/vtb/ob (all dead here)
        T(W1 + fOff, 1024, 4096, wT);
        gemm128n<1><<<512, 256, 0, stream>>>(
            g, wT, b1 + i * 4096, nullptr, nullptr, ffb, nullptr, nullptr, 4096);
        T(W2 + fOff, 4096, 1024, wT);
        gemm_bt<0, 64, 64, 1><<<dim3(16, 32), 256, 0, stream>>>(
            ffb, wT, b2 + i * 1024, nullptr, nullptr, tb, nullptr, nullptr,
            4096, 1024, 4096);
        ln_res<0, 0><<<4096, 256, 0, stream>>>(g, tb, n2s + i * 1024, n2b + i * 1024, g);
        gin = g;
    }

    // local(2)/local(4) fused to M=3072, inside `big` (attn/ff bufs dead)
    uint16_t* xsc = (uint16_t*)(big);            // 3072x1024
    uint16_t* lk  = (uint16_t*)(big + 8 * MB);   // 3072x512
    uint16_t* mo  = (uint16_t*)(big + 16 * MB);  // 3072x1024
    uint16_t* yy  = (uint16_t*)(big + 24 * MB);  // 3072x1024 (y2;y4)
    copy_rows_f32<<<2048, 256, 0, stream>>>(x, xsc, 9);
    copy_rows_f32<<<1024, 256, 0, stream>>>(x, xsc + (size_t)2048 * 1024, 8);
    uint16_t* WbT = wT;                          // 512x1024
    uint16_t* WmT = wT + (size_t)512 * 1024;     // 1024x512
    T(Wb, 1024, 512, WbT);
    T(Wm, 512, 1024, WmT);
    gemm_bt<0, 64, 64, 1><<<dim3(8, 24), 256, 0, stream>>>(
        xsc, WbT, bb, nullptr, nullptr, lk, nullptr, nullptr, 3072, 512, 1024);
    gemm_bt<0, 64, 64, 1><<<dim3(16, 24), 256, 0, stream>>>(
        lk, WmT, bm, nullptr, nullptr, mo, nullptr, nullptr, 3072, 1024, 512);
    ln_res<0, 0><<<3072, 256, 0, stream>>>(xsc, mo, ln1s, ln1b, yy);
    uint16_t* y2 = yy;
    uint16_t* y4 = yy + (size_t)2048 * 1024;

    add3<<<4096, 256, 0, stream>>>(g, y2, y4, g);                  // g = output
    ln_res<1, 0><<<4096, 256, 0, stream>>>(g, x, ln2s, ln2b, hb);  // h
    T(Wf1, 1024, 4096, wT);
    gemm128n<1><<<512, 256, 0, stream>>>(
        g, wT, bf1, nullptr, nullptr, ffb, nullptr, nullptr, 4096);
    T(Wf2, 4096, 1024, wT);
    gemm_bt<0, 64, 64, 1><<<dim3(16, 32), 256, 0, stream>>>(
        ffb, wT, bf2, nullptr, nullptr, tb, nullptr, nullptr, 4096, 1024, 4096);
    ln_res<0, 1><<<4096, 256, 0, stream>>>(hb, tb, ln3s, ln3b, d_out);  // fp32
}

// Round 5
// 720.515 us; speedup vs baseline: 1.0613x; 1.0613x over previous
//
#include <hip/hip_runtime.h>
#include <stdint.h>

// ---------------------------------------------------------------------------
// Uncond_MTPN_EncoderLayer: B=4 S=1024 D=1024 Fd=4096 M=512 H=16 HD=64 L=2
// Inputs fp32, output fp32, internal bf16 MFMA + fp32 accum.
// Round 15: FF2-class gemm_bt (46.3us, MfmaUtil 29%, all pipes <35% = stall-
// bound on the vmcnt(0) barrier drain) converted to the R12-verified counted-
// vmcnt 3-slot ring (one s_barrier + vmcnt(6) per K-tile, loads stay in
// flight).  Plus launch-count cuts: QKV transposes batched via grid.z (3->1),
// add3+ln_res<1,0> fused into add3_ln (one launch + 8.4MB less traffic).
// gemm128n (R12) and flash_attn (R13) unchanged.
// ---------------------------------------------------------------------------

typedef short   s16x8 __attribute__((ext_vector_type(8)));
typedef float   f32x4 __attribute__((ext_vector_type(4)));
typedef uint16_t u16x8 __attribute__((ext_vector_type(8)));
typedef uint16_t u16x4 __attribute__((ext_vector_type(4)));

__device__ __forceinline__ float bf2f(uint16_t h) {
    union { uint32_t u; float f; } c; c.u = ((uint32_t)h) << 16; return c.f;
}
__device__ __forceinline__ uint16_t f2bf(float f) {
    union { float f; uint32_t u; } c; c.f = f;
    uint32_t u = c.u;
    u += 0x7fffu + ((u >> 16) & 1u);       // round-to-nearest-even
    return (uint16_t)(u >> 16);
}
// packed RNE f32x2 -> bf16x2 (hardware; same rounding as f2bf)
__device__ __forceinline__ uint32_t cvt_pk_bf16(float lo, float hi) {
    uint32_t r;
    asm("v_cvt_pk_bf16_f32 %0, %1, %2" : "=v"(r) : "v"(lo), "v"(hi));
    return r;
}

__device__ __forceinline__ void g2l16(const uint16_t* g, uint16_t* l) {
    __builtin_amdgcn_global_load_lds(
        (const __attribute__((address_space(1))) void*)g,
        (__attribute__((address_space(3))) void*)l, 16, 0, 0);
}

// ---------------------------------------------------------------------------
// gemm128n: C[4096,N] = A[4096,1024] @ Bt[N,1024]^T + bias.  K=1024 fixed.
// 128x256 tile, 256 threads (4 waves, 1M x 4N), BK=32, 3-slot LDS ring (72KB)
// -> 2 blocks/CU.  Per K-tile: {stage(t+2); 12 ds_read_b128; lgkmcnt(0);
// 32 MFMA; vmcnt(6); s_barrier}.  Counted vmcnt keeps 6 loads in flight
// across the barrier; co-resident block fills residual stalls.
// MODE 1: bias+relu -> C0.  MODE 3: QKV fused (Q->C0, K->C1, V^T->C2).
// Hazards: stage(t+2)->slot (t-1)%3, readers drained at tile-(t-1) barrier;
// vmcnt(6)+barrier at tile end lands tile t+1 for ALL waves.
// Grid: 32 m-blocks = 8 XCD groups x 4; id&7 selects XCD group, n streamed.
// ---------------------------------------------------------------------------
template<int MODE>
__global__ __launch_bounds__(256, 2) void gemm128n(
    const uint16_t* __restrict__ A, const uint16_t* __restrict__ Bt,
    const float* __restrict__ bias0, const float* __restrict__ bias1,
    const float* __restrict__ bias2,
    uint16_t* __restrict__ C0, uint16_t* __restrict__ C1,
    uint16_t* __restrict__ C2,
    int N)
{
    // ring: A 3 x (128x32) = 24 KB, B 3 x (256x32) = 48 KB; epilogue 66 KB
    __shared__ __align__(16) uint16_t smem[36864];
    uint16_t* sA = smem;             // 3 x 4096 elems
    uint16_t* sB = smem + 12288;     // 3 x 8192 elems

    const int t    = threadIdx.x;
    const int w    = t >> 6;
    const int lane = t & 63;
    const int qd   = lane >> 4;
    const int cc   = lane & 15;
    const int wn   = w * 64;

    const int id  = blockIdx.x;
    const int loc = id >> 3;
    const int bm  = (id & 7) * 4 + (loc & 3);   // 32 m-blocks: 8 XCDs x 4
    const int bn  = loc >> 2;
    const int m0  = bm * 128;
    const int n0  = bn * 256;

    const float* bp = bias0;
    int n0c = n0;
    if (MODE == 3) {
        int seg = n0 >> 10;
        n0c = n0 & 1023;
        bp = (seg == 0) ? bias0 : (seg == 1) ? bias1 : bias2;
    }
    float bb[4];
#pragma unroll
    for (int j = 0; j < 4; ++j) bb[j] = bp[n0c + wn + j * 16 + cc];

    // fragment read offsets (XOR swizzle on 16B k-chunks; key = (row>>1)&3)
    int offA[8], offB[4];
#pragma unroll
    for (int i = 0; i < 8; ++i) {
        int ml = i * 16 + cc;
        offA[i] = ml * 32 + ((qd ^ ((ml >> 1) & 3)) * 8);
    }
#pragma unroll
    for (int j = 0; j < 4; ++j) {
        int nl = wn + j * 16 + cc;
        offB[j] = nl * 32 + ((qd ^ ((nl >> 1) & 3)) * 8);
    }

    // staging maps (pre-swizzled global source, linear LDS dest)
    const uint16_t* pA[2]; int ldA[2];
#pragma unroll
    for (int is = 0; is < 2; ++is) {
        int gc = is * 256 + t;
        int row = gc >> 2, ph = gc & 3;
        pA[is]  = A + (size_t)(m0 + row) * 1024 + (ph ^ ((row >> 1) & 3)) * 8;
        ldA[is] = (is * 256 + w * 64) * 8;
    }
    const uint16_t* pB[4]; int ldB[4];
#pragma unroll
    for (int is = 0; is < 4; ++is) {
        int gc = is * 256 + t;
        int row = gc >> 2, ph = gc & 3;
        pB[is]  = Bt + (size_t)(n0 + row) * 1024 + (ph ^ ((row >> 1) & 3)) * 8;
        ldB[is] = (is * 256 + w * 64) * 8;
    }
    auto stage = [&](int tt, int slot) {
        int kt = tt * 32;
        uint16_t* dA = sA + slot * 4096;
        uint16_t* dB = sB + slot * 8192;
#pragma unroll
        for (int is = 0; is < 2; ++is) g2l16(pA[is] + kt, dA + ldA[is]);
#pragma unroll
        for (int is = 0; is < 4; ++is) g2l16(pB[is] + kt, dB + ldB[is]);
    };

    f32x4 acc[8][4];
#pragma unroll
    for (int i = 0; i < 8; ++i)
#pragma unroll
        for (int j = 0; j < 4; ++j) acc[i][j] = (f32x4)0.0f;

    // prologue: tiles 0,1 in flight; land tile 0 (12 issued, keep 6)
    stage(0, 0); stage(1, 1);
    asm volatile("s_waitcnt vmcnt(6)" ::: "memory");
    __builtin_amdgcn_s_barrier();

    int cur = 0, pf = 2;
#pragma unroll 1
    for (int kt = 0; kt < 32; ++kt) {
        const uint16_t* sa = sA + cur * 4096;
        const uint16_t* sb = sB + cur * 8192;
        s16x8 av[8], bv[4];
#pragma unroll
        for (int j = 0; j < 4; ++j) bv[j] = *(const s16x8*)(sb + offB[j]);
#pragma unroll
        for (int i = 0; i < 8; ++i) av[i] = *(const s16x8*)(sa + offA[i]);
        if (kt < 30) stage(kt + 2, pf);        // issue while ds_reads in flight
        asm volatile("s_waitcnt lgkmcnt(0)" ::: "memory");
        __builtin_amdgcn_sched_barrier(0);
        __builtin_amdgcn_s_setprio(1);
#pragma unroll
        for (int i = 0; i < 8; ++i)
#pragma unroll
            for (int j = 0; j < 4; ++j)
                acc[i][j] = __builtin_amdgcn_mfma_f32_16x16x32_bf16(
                    av[i], bv[j], acc[i][j], 0, 0, 0);
        __builtin_amdgcn_s_setprio(0);
        // tile kt+1 (oldest 6 of <=12 outstanding) must land before barrier
        if (kt < 30)       { asm volatile("s_waitcnt vmcnt(6)" ::: "memory"); }
        else if (kt == 30) { asm volatile("s_waitcnt vmcnt(0)" ::: "memory"); }
        __builtin_amdgcn_s_barrier();
        pf = cur;
        cur = (cur == 2) ? 0 : cur + 1;
    }

    // ------------------------------ epilogue -------------------------------
    // C/D layout: col=lane&15, row=(lane>>4)*4+reg  [m89 verified]
    if (MODE == 3 && (n0 >> 10) == 2) {
        // V^T: C2[((b*16+hh)*64+d)*1024 + s], 4 consecutive s per u16x4
#pragma unroll
        for (int j = 0; j < 4; ++j) {
            int c = n0c + wn + j * 16 + cc;
            int hh = c >> 6, d = c & 63;
#pragma unroll
            for (int i = 0; i < 8; ++i) {
                int rb = m0 + i * 16 + qd * 4;
                int b = rb >> 10, s = rb & 1023;
                u16x4 o;
#pragma unroll
                for (int r = 0; r < 4; ++r) o[r] = f2bf(acc[i][j][r] + bb[j]);
                *(u16x4*)(C2 + ((size_t)((b * 16 + hh) * 64 + d)) * 1024 + s) = o;
            }
        }
        return;
    }
    {
        uint16_t* C = C0;
        int Nc = N;
        if (MODE == 3) {
            int seg = n0 >> 10;
            C = (seg == 0) ? C0 : C1;
            Nc = 1024;
        }
        constexpr int ST = 264;            // 256 + 8 pad
        // final K-loop barrier followed all lgkmcnt(0) drains: smem is dead
#pragma unroll
        for (int i = 0; i < 8; ++i)
#pragma unroll
            for (int j = 0; j < 4; ++j) {
                f32x4 v = acc[i][j];
#pragma unroll
                for (int r = 0; r < 4; ++r) {
                    float val = v[r] + bb[j];
                    if (MODE == 1) val = fmaxf(val, 0.0f);
                    smem[(i * 16 + qd * 4 + r) * ST + wn + j * 16 + cc] = f2bf(val);
                }
            }
        __syncthreads();
#pragma unroll
        for (int p = 0; p < 16; ++p) {
            int row  = p * 8 + (t >> 5);
            int colc = (t & 31) * 8;
            u16x8 v = *(const u16x8*)(smem + row * ST + colc);
            *(u16x8*)(C + (size_t)(m0 + row) * Nc + n0c + colc) = v;
        }
    }
}

// ---------------------------------------------------------------------------
// GEMM: C[M,N] = A[M,K] @ B[K,N] + bias, B supplied as Bt[N,K] (bf16).
// R15: counted-vmcnt 3-slot ring (ported from gemm128n, verified R12/R13):
// per K-tile {12 ds_read_b128; stage(t+2); lgkmcnt(0); 16 MFMA; vmcnt(6);
// s_barrier}.  LDS 3x(128+BN)xBK = 72KB at BN=64/BK=64 -> 2 blocks/CU.
// MODE 0: bias -> C0 (LDS-exchange vectorized epilogue).
// MODE 1: bias+relu -> C0.  (MODE 3 kept for completeness.)
// Grid remap: id%8 (~XCD) selects an m-panel group; n streamed within group.
// ---------------------------------------------------------------------------
template<int MODE, int BN, int BK>
__global__ __launch_bounds__(256, 2) void gemm_bt(
    const uint16_t* __restrict__ A, const uint16_t* __restrict__ Bt,
    const float* __restrict__ bias0, const float* __restrict__ bias1,
    const float* __restrict__ bias2,
    uint16_t* __restrict__ C0, uint16_t* __restrict__ C1,
    uint16_t* __restrict__ C2,
    int M, int N, int K)
{
    constexpr int JN    = BN / 32;
    constexpr int KS    = BK / 32;
    constexpr int CPR   = BK / 8;
    constexpr int LG    = (BK == 32) ? 2 : 3;
    constexpr int RA    = (128 * BK / 8) / 256;
    constexpr int RB    = (BN  * BK / 8) / 256;
    constexpr int SLOTA = 128 * BK;
    constexpr int SLOTB = BN * BK;
    constexpr int STG   = 3 * (SLOTA + SLOTB);             // ring elems
    constexpr int EPI   = (MODE == 3) ? 0 : 128 * (BN + 8); // exchange elems
    constexpr int SMEM  = (STG > EPI) ? STG : EPI;
    __shared__ __align__(16) uint16_t smem[SMEM];
    uint16_t* sA = smem;                    // 3 x SLOTA
    uint16_t* sB = smem + 3 * SLOTA;        // 3 x SLOTB

    const int t    = threadIdx.x;
    const int w    = t >> 6;
    const int lane = t & 63;
    const int qd   = lane >> 4;
    const int cc   = lane & 15;

    int bm, bn;
    {
        int gx = gridDim.x, gy = gridDim.y;
        if ((gy & 7) == 0) {
            int id   = blockIdx.y * gx + blockIdx.x;
            int gpg  = gy >> 3;
            int rest = id >> 3;
            bm = (id & 7) * gpg + rest % gpg;
            bn = rest / gpg;
        } else { bm = blockIdx.y; bn = blockIdx.x; }
    }
    const int m0 = bm * 128;
    const int n0 = bn * BN;
    const int wm = (w >> 1) * 64;
    const int wn = (w & 1) * (BN / 2);

    auto key = [](int row) -> int {
        return (BK == 32) ? ((row >> 1) & 3) : (row & 7);
    };

    f32x4 acc[4][JN];
#pragma unroll
    for (int i = 0; i < 4; ++i)
#pragma unroll
        for (int j = 0; j < JN; ++j) acc[i][j] = (f32x4)0.0f;

    // staging maps (pre-swizzled global source, linear LDS dest)
    int rA[RA], kA[RA];
#pragma unroll
    for (int is = 0; is < RA; ++is) {
        int gc = is * 256 + t;
        int row = gc >> LG, ph = gc & (CPR - 1);
        rA[is] = row;
        kA[is] = (ph ^ key(row)) * 8;
    }
    int rB[RB], kB[RB];
#pragma unroll
    for (int is = 0; is < RB; ++is) {
        int gc = is * 256 + t;
        int row = gc >> LG, ph = gc & (CPR - 1);
        rB[is] = row;
        kB[is] = (ph ^ key(row)) * 8;
    }
    int offA[4][KS], offB[JN][KS];
#pragma unroll
    for (int i = 0; i < 4; ++i) {
        int ml = wm + i * 16 + cc;
#pragma unroll
        for (int ks = 0; ks < KS; ++ks)
            offA[i][ks] = ml * BK + ((ks * 4 + qd) ^ key(ml)) * 8;
    }
#pragma unroll
    for (int j = 0; j < JN; ++j) {
        int nl = wn + j * 16 + cc;
#pragma unroll
        for (int ks = 0; ks < KS; ++ks)
            offB[j][ks] = nl * BK + ((ks * 4 + qd) ^ key(nl)) * 8;
    }

    auto stage = [&](int kt, int slot) {
#pragma unroll
        for (int is = 0; is < RA; ++is)
            g2l16(A + (size_t)(m0 + rA[is]) * K + kt + kA[is],
                  sA + (size_t)slot * SLOTA + (size_t)(is * 256 + w * 64) * 8);
#pragma unroll
        for (int is = 0; is < RB; ++is)
            g2l16(Bt + (size_t)(n0 + rB[is]) * K + kt + kB[is],
                  sB + (size_t)slot * SLOTB + (size_t)(is * 256 + w * 64) * 8);
    };

    const int NT = K / BK;      // all call sites: NT >= 8
    // prologue: tiles 0,1 in flight; land tile 0 (12 issued, keep 6)
    stage(0, 0); stage(BK, 1);
    asm volatile("s_waitcnt vmcnt(6)" ::: "memory");
    __builtin_amdgcn_s_barrier();

    int cur = 0, pf = 2;
#pragma unroll 1
    for (int tt = 0; tt < NT; ++tt) {
        const uint16_t* sa = sA + cur * SLOTA;
        const uint16_t* sb = sB + cur * SLOTB;
        s16x8 af[KS][4], bv[KS][JN];
#pragma unroll
        for (int ks = 0; ks < KS; ++ks) {
#pragma unroll
            for (int j = 0; j < JN; ++j) bv[ks][j] = *(const s16x8*)(sb + offB[j][ks]);
#pragma unroll
            for (int i = 0; i < 4; ++i)  af[ks][i] = *(const s16x8*)(sa + offA[i][ks]);
        }
        if (tt + 2 < NT) stage((tt + 2) * BK, pf);  // issue while ds in flight
        asm volatile("s_waitcnt lgkmcnt(0)" ::: "memory");
        __builtin_amdgcn_sched_barrier(0);
        __builtin_amdgcn_s_setprio(1);
#pragma unroll
        for (int ks = 0; ks < KS; ++ks)
#pragma unroll
            for (int i = 0; i < 4; ++i)
#pragma unroll
                for (int j = 0; j < JN; ++j)
                    acc[i][j] = __builtin_amdgcn_mfma_f32_16x16x32_bf16(
                        af[ks][i], bv[ks][j], acc[i][j], 0, 0, 0);
        __builtin_amdgcn_s_setprio(0);
        // tile tt+1 (oldest 6 of <=12 outstanding) must land before barrier
        if (tt + 2 < NT)      { asm volatile("s_waitcnt vmcnt(6)" ::: "memory"); }
        else if (tt + 2 == NT){ asm volatile("s_waitcnt vmcnt(0)" ::: "memory"); }
        __builtin_amdgcn_s_barrier();
        pf = cur;
        cur = (cur == 2) ? 0 : cur + 1;
    }

    // C/D layout: col=lane&15, row=(lane>>4)*4+reg  [m89 verified]
    if (MODE == 3) {
#pragma unroll
        for (int j = 0; j < JN; ++j) {
            int col = n0 + wn + j * 16 + cc;
            int seg = col >> 10;
            const float* bp = (seg == 0) ? bias0 : (seg == 1) ? bias1 : bias2;
            float bb = bp[col & 1023];
#pragma unroll
            for (int i = 0; i < 4; ++i) {
                f32x4 v = acc[i][j];
#pragma unroll
                for (int r = 0; r < 4; ++r) {
                    float val = v[r] + bb;
                    int row = m0 + wm + i * 16 + qd * 4 + r;
                    if (col < 1024) {
                        C0[(size_t)row * 1024 + col] = f2bf(val);
                    } else if (col < 2048) {
                        C1[(size_t)row * 1024 + (col - 1024)] = f2bf(val);
                    } else {
                        int c = col - 2048;
                        int b = row >> 10, s = row & 1023;
                        int hh = c >> 6, d = c & 63;
                        C2[((size_t)(b * 16 + hh) * 64 + d) * 1024 + s] = f2bf(val);
                    }
                }
            }
        }
    } else {
        // LDS-exchange epilogue: scatter to padded tile, vector readback/store
        constexpr int ST = BN + 8;           // elem stride: 2-way max aliasing
        // (final K-loop barrier already protects smem reuse)
#pragma unroll
        for (int j = 0; j < JN; ++j) {
            int col = wn + j * 16 + cc;
            float bb = bias0[n0 + col];
#pragma unroll
            for (int i = 0; i < 4; ++i) {
                f32x4 v = acc[i][j];
#pragma unroll
                for (int r = 0; r < 4; ++r) {
                    float val = v[r] + bb;
                    if (MODE == 1) val = fmaxf(val, 0.0f);
                    smem[(wm + i * 16 + qd * 4 + r) * ST + col] = f2bf(val);
                }
            }
        }
        __syncthreads();
        constexpr int NP  = 128 * BN / 2048;   // u16x8 rounds (8 or 4)
        constexpr int TPR = BN / 8;            // threads per row (16 or 8)
#pragma unroll
        for (int p = 0; p < NP; ++p) {
            int row  = p * (256 / TPR) + t / TPR;
            int colc = (t % TPR) * 8;
            u16x8 v = *(const u16x8*)(smem + row * ST + colc);
            *(u16x8*)(C0 + (size_t)(m0 + row) * N + n0 + colc) = v;
        }
    }
}

// ---------------------------------------------------------------------------
// Flash attention, no-max softmax (scores tiny; softmax shift-invariant).
// Block = (64 q rows, head).  1D grid 1024; id&7 (~XCD) owns heads 8x..8x+7.
// Pad 76 elem (152 B): frag reads/Ps writes land 2 lanes/bank (free).
// R13: K/V reg-prefetch (T14), packed cvt_pk P-stores, Q frags hoisted
// (QPs buffer = Q staging, then reused as P exchange; 29.2 KB LDS).
// ---------------------------------------------------------------------------
#define FA_P 76
__global__ __launch_bounds__(256) void flash_attn(
    const uint16_t* __restrict__ Q, const uint16_t* __restrict__ K,
    const uint16_t* __restrict__ Vt, uint16_t* __restrict__ O)
{
    __shared__ __align__(16) uint16_t QPs[64 * FA_P];  // Q stage, then P
    __shared__ __align__(16) uint16_t Ks[64 * FA_P];
    __shared__ __align__(16) uint16_t Vs[64 * FA_P];   // Vs[d][kpos]

    const int t    = threadIdx.x;
    const int w    = t >> 6;
    const int lane = t & 63;
    const int qd   = lane >> 4;
    const int cc   = lane & 15;
    const int id   = blockIdx.x;
    const int xg   = id & 7;
    const int loc  = id >> 3;
    const int bh   = xg * 8 + (loc >> 4);
    const int qblk = loc & 15;
    const int b    = bh >> 4, hh = bh & 15;
    const size_t rowbase = (size_t)b * 1024;

    // staging geometry: thread covers 2 chunks (row, 8-elem chunk)
    int rr[2], ch8[2], lws[2];
    const uint16_t* Kp[2];
    const uint16_t* Vp[2];
#pragma unroll
    for (int is = 0; is < 2; ++is) {
        int c   = is * 256 + t;
        rr[is]  = c >> 3;
        ch8[is] = (c & 7) * 8;
        lws[is] = rr[is] * FA_P + ch8[is];
        Kp[is]  = K  + (rowbase + rr[is]) * 1024 + hh * 64 + ch8[is];
        Vp[is]  = Vt + ((size_t)(bh * 64 + rr[is])) * 1024 + ch8[is];
    }

    // prefetch K/V tile 0 into regs (lands during Q staging + barriers)
    u16x8 kr[2], vr[2];
#pragma unroll
    for (int is = 0; is < 2; ++is) {
        kr[is] = *(const u16x8*)(Kp[is]);
        vr[is] = *(const u16x8*)(Vp[is]);
    }

    // stage Q, hoist fragments to regs (loop-invariant)
#pragma unroll
    for (int is = 0; is < 2; ++is)
        *(u16x8*)(QPs + lws[is]) =
            *(const u16x8*)(Q + (rowbase + qblk * 64 + rr[is]) * 1024 + hh * 64 + ch8[is]);
    __syncthreads();
    s16x8 aq0 = *(const s16x8*)(QPs + (w * 16 + cc) * FA_P + qd * 8);
    s16x8 aq1 = *(const s16x8*)(QPs + (w * 16 + cc) * FA_P + 32 + qd * 8);
    __syncthreads();   // drains lgkm: all waves' Q reads done before P writes

    f32x4 o[4];
    float lrow[4] = {0.0f, 0.0f, 0.0f, 0.0f};
#pragma unroll
    for (int j = 0; j < 4; ++j) o[j] = (f32x4)0.0f;

#pragma unroll 1
    for (int kb = 64; kb <= 1024; kb += 64) {
        // write prefetched tile to LDS (regs free after issue)
#pragma unroll
        for (int is = 0; is < 2; ++is) {
            *(u16x8*)(Ks + lws[is]) = kr[is];
            *(u16x8*)(Vs + lws[is]) = vr[is];
        }
        if (kb < 1024) {   // issue next tile's loads; land during compute
#pragma unroll
            for (int is = 0; is < 2; ++is) {
                kr[is] = *(const u16x8*)(Kp[is] + (size_t)kb * 1024);
                vr[is] = *(const u16x8*)(Vp[is] + kb);
            }
        }
        __syncthreads();

        f32x4 sc[4];
#pragma unroll
        for (int j = 0; j < 4; ++j) {
            s16x8 b0 = *(const s16x8*)(Ks + (j * 16 + cc) * FA_P + qd * 8);
            s16x8 b1 = *(const s16x8*)(Ks + (j * 16 + cc) * FA_P + 32 + qd * 8);
            sc[j] = __builtin_amdgcn_mfma_f32_16x16x32_bf16(aq0, b0, (f32x4)0.0f, 0, 0, 0);
            sc[j] = __builtin_amdgcn_mfma_f32_16x16x32_bf16(aq1, b1, sc[j], 0, 0, 0);
        }

#pragma unroll
        for (int r = 0; r < 4; ++r) {
            float p0 = __expf(sc[0][r] * 0.125f);
            float p1 = __expf(sc[1][r] * 0.125f);
            float p2 = __expf(sc[2][r] * 0.125f);
            float p3 = __expf(sc[3][r] * 0.125f);
            lrow[r] += (p0 + p1) + (p2 + p3);
            int prow = (w * 16 + qd * 4 + r) * FA_P + cc;
            uint32_t pk01 = cvt_pk_bf16(p0, p1);
            uint32_t pk23 = cvt_pk_bf16(p2, p3);
            QPs[prow]      = (uint16_t)pk01;
            QPs[prow + 16] = (uint16_t)(pk01 >> 16);
            QPs[prow + 32] = (uint16_t)pk23;
            QPs[prow + 48] = (uint16_t)(pk23 >> 16);
        }

        // P rows w*16..w*16+15 written and read by the SAME wave: no barrier
#pragma unroll
        for (int ks = 0; ks < 2; ++ks) {
            s16x8 ap = *(const s16x8*)(QPs + (w * 16 + cc) * FA_P + ks * 32 + qd * 8);
#pragma unroll
            for (int j = 0; j < 4; ++j) {
                s16x8 bv = *(const s16x8*)(Vs + (j * 16 + cc) * FA_P + ks * 32 + qd * 8);
                o[j] = __builtin_amdgcn_mfma_f32_16x16x32_bf16(ap, bv, o[j], 0, 0, 0);
            }
        }
        __syncthreads();   // all Ks/Vs reads done -> next iter may overwrite
    }

#pragma unroll
    for (int r = 0; r < 4; ++r) {
        float rs = lrow[r];
        rs += __shfl_xor(rs, 1);
        rs += __shfl_xor(rs, 2);
        rs += __shfl_xor(rs, 4);
        rs += __shfl_xor(rs, 8);
        float inv = 1.0f / rs;
        size_t grow = rowbase + qblk * 64 + w * 16 + qd * 4 + r;
#pragma unroll
        for (int j = 0; j < 4; ++j)
            O[grow * 1024 + hh * 64 + j * 16 + cc] = f2bf(o[j][r] * inv);
    }
}

// ---------------------------------------------------------------------------
// out = LayerNorm(A + B) * scale + bias over rows of 1024.
// A bf16;  B bf16 (BT=0) or fp32 (BT=1);  scale/bias fp32.
// F32OUT=1 stores fp32 (the network output); else bf16.  1 block/row.
// ---------------------------------------------------------------------------
template<int BT, int F32OUT>
__global__ __launch_bounds__(256) void ln_res(
    const uint16_t* __restrict__ A, const void* __restrict__ Bp,
    const float* __restrict__ S, const float* __restrict__ Bi,
    void* __restrict__ outp)
{
    const int row = blockIdx.x, t = threadIdx.x;
    const int w = t >> 6, lane = t & 63;
    u16x4 a4 = *(const u16x4*)(A + (size_t)row * 1024 + t * 4);
    float bvals[4];
    if (BT == 0) {
        u16x4 b4 = *(const u16x4*)((const uint16_t*)Bp + (size_t)row * 1024 + t * 4);
#pragma unroll
        for (int e = 0; e < 4; ++e) bvals[e] = bf2f(b4[e]);
    } else {
        float4 b4 = *(const float4*)((const float*)Bp + (size_t)row * 1024 + t * 4);
        bvals[0] = b4.x; bvals[1] = b4.y; bvals[2] = b4.z; bvals[3] = b4.w;
    }
    float v[4], sum = 0.0f, sq = 0.0f;
#pragma unroll
    for (int e = 0; e < 4; ++e) {
        v[e] = bf2f(a4[e]) + bvals[e];
        sum += v[e];
        sq  += v[e] * v[e];
    }
#pragma unroll
    for (int d = 1; d < 64; d <<= 1) {
        sum += __shfl_xor(sum, d);
        sq  += __shfl_xor(sq, d);
    }
    __shared__ float rs[4], rq[4];
    if (lane == 0) { rs[w] = sum; rq[w] = sq; }
    __syncthreads();
    sum = rs[0] + rs[1] + rs[2] + rs[3];
    sq  = rq[0] + rq[1] + rq[2] + rq[3];
    float mean = sum * (1.0f / 1024.0f);
    float var  = sq * (1.0f / 1024.0f) - mean * mean;
    float rstd = rsqrtf(var + 1e-5f);
    float4 s4  = *(const float4*)(S + t * 4);
    float4 bi4 = *(const float4*)(Bi + t * 4);
    float r0 = (v[0] - mean) * rstd * s4.x + bi4.x;
    float r1 = (v[1] - mean) * rstd * s4.y + bi4.y;
    float r2 = (v[2] - mean) * rstd * s4.z + bi4.z;
    float r3 = (v[3] - mean) * rstd * s4.w + bi4.w;
    if (F32OUT) {
        *(float4*)((float*)outp + (size_t)row * 1024 + t * 4) =
            make_float4(r0, r1, r2, r3);
    } else {
        u16x4 o4;
        o4[0] = f2bf(r0); o4[1] = f2bf(r1); o4[2] = f2bf(r2); o4[3] = f2bf(r3);
        *(u16x4*)((uint16_t*)outp + (size_t)row * 1024 + t * 4) = o4;
    }
}

// ---------------------------------------------------------------------------
// Fused: out = g + pad(y2) + pad(y4)  (stored to g, bf16)
//        h   = LayerNorm(out + x) * s + b  (stored bf16)
// One block per row; replaces add3 + ln_res<1,0> (saves a launch + 8.4 MB).
// ---------------------------------------------------------------------------
__global__ __launch_bounds__(256) void add3_ln(
    uint16_t* __restrict__ g, const uint16_t* __restrict__ y2,
    const uint16_t* __restrict__ y4, const float* __restrict__ x,
    const float* __restrict__ S, const float* __restrict__ Bi,
    uint16_t* __restrict__ h)
{
    const int row = blockIdx.x, t = threadIdx.x;
    const int w = t >> 6, lane = t & 63;
    const int b = row >> 10, s = row & 1023;
    const size_t e = (size_t)row * 1024 + t * 4;
    u16x4 gv = *(const u16x4*)(g + e);
    float v[4];
#pragma unroll
    for (int k = 0; k < 4; ++k) v[k] = bf2f(gv[k]);
    if (s >= 512) {
        u16x4 a = *(const u16x4*)(y2 + ((size_t)(b * 512 + s - 512)) * 1024 + t * 4);
#pragma unroll
        for (int k = 0; k < 4; ++k) v[k] += bf2f(a[k]);
    }
    if (s >= 768) {
        u16x4 a = *(const u16x4*)(y4 + ((size_t)(b * 256 + s - 768)) * 1024 + t * 4);
#pragma unroll
        for (int k = 0; k < 4; ++k) v[k] += bf2f(a[k]);
    }
    u16x4 o4;
#pragma unroll
    for (int k = 0; k < 4; ++k) o4[k] = f2bf(v[k]);
    *(u16x4*)(g + e) = o4;                       // out = g+pad(y2)+pad(y4)

    float4 xv = *(const float4*)(x + e);
    float v2[4] = { v[0] + xv.x, v[1] + xv.y, v[2] + xv.z, v[3] + xv.w };
    float sum = 0.0f, sq = 0.0f;
#pragma unroll
    for (int k = 0; k < 4; ++k) { sum += v2[k]; sq += v2[k] * v2[k]; }
#pragma unroll
    for (int d = 1; d < 64; d <<= 1) {
        sum += __shfl_xor(sum, d);
        sq  += __shfl_xor(sq, d);
    }
    __shared__ float rs[4], rq[4];
    if (lane == 0) { rs[w] = sum; rq[w] = sq; }
    __syncthreads();
    sum = rs[0] + rs[1] + rs[2] + rs[3];
    sq  = rq[0] + rq[1] + rq[2] + rq[3];
    float mean = sum * (1.0f / 1024.0f);
    float var  = sq * (1.0f / 1024.0f) - mean * mean;
    float rstd = rsqrtf(var + 1e-5f);
    float4 s4  = *(const float4*)(S + t * 4);
    float4 bi4 = *(const float4*)(Bi + t * 4);
    u16x4 ho;
    ho[0] = f2bf((v2[0] - mean) * rstd * s4.x + bi4.x);
    ho[1] = f2bf((v2[1] - mean) * rstd * s4.y + bi4.y);
    ho[2] = f2bf((v2[2] - mean) * rstd * s4.z + bi4.z);
    ho[3] = f2bf((v2[3] - mean) * rstd * s4.w + bi4.w);
    *(u16x4*)(h + e) = ho;
}

// gather last-st rows per batch from fp32 x, emit bf16
__global__ __launch_bounds__(256) void copy_rows_f32(
    const float* __restrict__ x, uint16_t* __restrict__ out, int lgst)
{
    size_t e = ((size_t)blockIdx.x * 256 + threadIdx.x) * 4;
    int row = (int)(e >> 10), col = (int)(e & 1023);
    int st = 1 << lgst;
    int b = row >> lgst, s = row & (st - 1);
    float4 a = *(const float4*)(x + ((size_t)(b * 1024 + (1024 - st) + s)) * 1024 + col);
    u16x4 o4;
    o4[0] = f2bf(a.x); o4[1] = f2bf(a.y); o4[2] = f2bf(a.z); o4[3] = f2bf(a.w);
    *(u16x4*)(out + e) = o4;
}

// Wt[N,K] = bf16(W[K,N]^T), fp32 source.  64x64 tiles, float4 in, u16x8 out.
// grid.z selects among up to 3 same-shape sources (dst offset z*Kd*Nd).
__global__ __launch_bounds__(256) void transpose_k(
    const float* __restrict__ W0, const float* __restrict__ W1,
    const float* __restrict__ W2, uint16_t* __restrict__ Wt, int Kd, int Nd)
{
    const int z = blockIdx.z;
    const float* W = (z == 0) ? W0 : (z == 1) ? W1 : W2;
    uint16_t* dst = Wt + (size_t)z * Kd * Nd;
    __shared__ uint16_t tile[64][68];
    const int t  = threadIdx.x;
    const int n0 = blockIdx.x * 64, k0 = blockIdx.y * 64;
#pragma unroll
    for (int p = 0; p < 4; ++p) {
        int k  = p * 16 + (t >> 4);
        int nn = (t & 15) * 4;
        float4 a = *(const float4*)(W + (size_t)(k0 + k) * Nd + n0 + nn);
        tile[nn + 0][k] = f2bf(a.x);
        tile[nn + 1][k] = f2bf(a.y);
        tile[nn + 2][k] = f2bf(a.z);
        tile[nn + 3][k] = f2bf(a.w);
    }
    __syncthreads();
#pragma unroll
    for (int p = 0; p < 2; ++p) {
        int nn = p * 32 + (t >> 3);
        int kk = (t & 7) * 8;
        u16x8 o = *(const u16x8*)(&tile[nn][kk]);
        *(u16x8*)(dst + (size_t)(n0 + nn) * Kd + k0 + kk) = o;
    }
}

// fp32 -> bf16 bulk convert
__global__ __launch_bounds__(256) void cvt(
    const float* __restrict__ src, uint16_t* __restrict__ dst)
{
    size_t i = ((size_t)blockIdx.x * 256 + threadIdx.x) * 8;
    float4 a = *(const float4*)(src + i);
    float4 b = *(const float4*)(src + i + 4);
    u16x8 o;
    o[0] = f2bf(a.x); o[1] = f2bf(a.y); o[2] = f2bf(a.z); o[3] = f2bf(a.w);
    o[4] = f2bf(b.x); o[5] = f2bf(b.y); o[6] = f2bf(b.z); o[7] = f2bf(b.w);
    *(u16x8*)(dst + i) = o;
}

// ---------------------------------------------------------------------------
extern "C" void kernel_launch(void* const* d_in, const int* in_sizes, int n_in,
                              void* d_out, int out_size, void* d_ws, size_t ws_size,
                              hipStream_t stream)
{
    const float* x    = (const float*)d_in[0];
    const float* Wq   = (const float*)d_in[1];
    const float* bq   = (const float*)d_in[2];
    const float* Wk   = (const float*)d_in[3];
    const float* bk   = (const float*)d_in[4];
    const float* Wv   = (const float*)d_in[5];
    const float* bv   = (const float*)d_in[6];
    const float* Wo   = (const float*)d_in[7];
    const float* bo   = (const float*)d_in[8];
    const float* W1   = (const float*)d_in[9];
    const float* b1   = (const float*)d_in[10];
    const float* W2   = (const float*)d_in[11];
    const float* b2   = (const float*)d_in[12];
    const float* n1s  = (const float*)d_in[13];
    const float* n1b  = (const float*)d_in[14];
    const float* n2s  = (const float*)d_in[15];
    const float* n2b  = (const float*)d_in[16];
    const float* ln1s = (const float*)d_in[17];
    const float* ln1b = (const float*)d_in[18];
    const float* ln2s = (const float*)d_in[19];
    const float* ln2b = (const float*)d_in[20];
    const float* ln3s = (const float*)d_in[21];
    const float* ln3b = (const float*)d_in[22];
    const float* Wb   = (const float*)d_in[23];
    const float* bb   = (const float*)d_in[24];
    const float* Wm   = (const float*)d_in[25];
    const float* bm   = (const float*)d_in[26];
    const float* Wf1  = (const float*)d_in[27];
    const float* bf1  = (const float*)d_in[28];
    const float* Wf2  = (const float*)d_in[29];
    const float* bf2  = (const float*)d_in[30];

    // ---- 64 MiB workspace layout ------------------------------------------
    char* ws = (char*)d_ws;
    const size_t MB = (size_t)1 << 20;
    uint16_t* g    = (uint16_t*)(ws);
    uint16_t* tb   = (uint16_t*)(ws + 8 * MB);
    char*     big  = ws + 16 * MB;
    uint16_t* qb   = (uint16_t*)(big);
    uint16_t* kbuf = (uint16_t*)(big + 8 * MB);
    uint16_t* vtb  = (uint16_t*)(big + 16 * MB);
    uint16_t* ob   = (uint16_t*)(big + 24 * MB);
    uint16_t* ffb  = (uint16_t*)(big);            // 32 MiB, attn bufs dead
    uint16_t* xbf  = (uint16_t*)(ws + 48 * MB);
    uint16_t* hb   = (uint16_t*)(ws + 48 * MB);   // reuses xbf slot
    uint16_t* wT   = (uint16_t*)(ws + 56 * MB);

    auto T = [&](const float* Wsrc, int Kd, int Nd, uint16_t* dst) {
        transpose_k<<<dim3(Nd / 64, Kd / 64, 1), 256, 0, stream>>>(
            Wsrc, Wsrc, Wsrc, dst, Kd, Nd);
    };

    cvt<<<2048, 256, 0, stream>>>(x, xbf);   // 4M elements

    const uint16_t* gin = xbf;
    for (int i = 0; i < 2; ++i) {
        const size_t wOff = (size_t)i * 1024 * 1024;
        const size_t fOff = (size_t)i * 1024 * 4096;
        // fused QKV: wT = [Wq^T ; Wk^T ; Wv^T]  (one batched launch, z=3)
        transpose_k<<<dim3(16, 16, 3), 256, 0, stream>>>(
            Wq + wOff, Wk + wOff, Wv + wOff, wT, 1024, 1024);
        gemm128n<3><<<384, 256, 0, stream>>>(
            gin, wT, bq + i * 1024, bk + i * 1024, bv + i * 1024,
            qb, kbuf, vtb, 3072);
        flash_attn<<<1024, 256, 0, stream>>>(qb, kbuf, vtb, ob);
        T(Wo + wOff, 1024, 1024, wT);
        gemm_bt<0, 64, 64><<<dim3(16, 32), 256, 0, stream>>>(
            ob, wT, bo + i * 1024, nullptr, nullptr, tb, nullptr, nullptr,
            4096, 1024, 1024);
        ln_res<0, 0><<<4096, 256, 0, stream>>>(gin, tb, n1s + i * 1024, n1b + i * 1024, g);
        // FF: ffb overlays qb/kbuf/vtb/ob (all dead here)
        T(W1 + fOff, 1024, 4096, wT);
        gemm128n<1><<<512, 256, 0, stream>>>(
            g, wT, b1 + i * 4096, nullptr, nullptr, ffb, nullptr, nullptr, 4096);
        T(W2 + fOff, 4096, 1024, wT);
        gemm_bt<0, 64, 64><<<dim3(16, 32), 256, 0, stream>>>(
            ffb, wT, b2 + i * 1024, nullptr, nullptr, tb, nullptr, nullptr,
            4096, 1024, 4096);
        ln_res<0, 0><<<4096, 256, 0, stream>>>(g, tb, n2s + i * 1024, n2b + i * 1024, g);
        gin = g;
    }

    // local(2)/local(4) fused to M=3072, inside `big` (attn/ff bufs dead)
    uint16_t* xsc = (uint16_t*)(big);            // 3072x1024
    uint16_t* lk  = (uint16_t*)(big + 8 * MB);   // 3072x512
    uint16_t* mo  = (uint16_t*)(big + 16 * MB);  // 3072x1024
    uint16_t* yy  = (uint16_t*)(big + 24 * MB);  // 3072x1024 (y2;y4)
    copy_rows_f32<<<2048, 256, 0, stream>>>(x, xsc, 9);
    copy_rows_f32<<<1024, 256, 0, stream>>>(x, xsc + (size_t)2048 * 1024, 8);
    uint16_t* WbT = wT;                          // 512x1024
    uint16_t* WmT = wT + (size_t)512 * 1024;     // 1024x512
    T(Wb, 1024, 512, WbT);
    T(Wm, 512, 1024, WmT);
    gemm_bt<0, 64, 64><<<dim3(8, 24), 256, 0, stream>>>(
        xsc, WbT, bb, nullptr, nullptr, lk, nullptr, nullptr, 3072, 512, 1024);
    gemm_bt<0, 64, 64><<<dim3(16, 24), 256, 0, stream>>>(
        lk, WmT, bm, nullptr, nullptr, mo, nullptr, nullptr, 3072, 1024, 512);
    ln_res<0, 0><<<3072, 256, 0, stream>>>(xsc, mo, ln1s, ln1b, yy);
    uint16_t* y2 = yy;
    uint16_t* y4 = yy + (size_t)2048 * 1024;

    // fused: g = g+pad(y2)+pad(y4);  hb = LN(g_new + x)
    add3_ln<<<4096, 256, 0, stream>>>(g, y2, y4, x, ln2s, ln2b, hb);
    T(Wf1, 1024, 4096, wT);
    gemm128n<1><<<512, 256, 0, stream>>>(
        g, wT, bf1, nullptr, nullptr, ffb, nullptr, nullptr, 4096);
    T(Wf2, 4096, 1024, wT);
    gemm_bt<0, 64, 64><<<dim3(16, 32), 256, 0, stream>>>(
        ffb, wT, bf2, nullptr, nullptr, tb, nullptr, nullptr, 4096, 1024, 4096);
    ln_res<0, 1><<<4096, 256, 0, stream>>>(hb, tb, ln3s, ln3b, d_out);  // fp32
}